// Round 1
// baseline (1693.784 us; speedup 1.0000x reference)
//
#include <hip/hip_runtime.h>
#include <hip/hip_bf16.h>

#define B_ 2
#define C_ 192
#define HEADS_ 8
#define CH_ 24
#define H_ 256
#define W_ 256
#define HW_ 65536

// ---------------- workspace layout (bytes) ----------------
// tmpQ  bf16 [B][192][HW]          @ 0          (50331648)
// tmpKV bf16 [B][384][HW]          @ 50331648   (100663296)
// G     f32  [B][8][24][24]        @ 150994944  (36864)
// sq    f32  [B][192]              @ 151031808  (1536)
// sk    f32  [B][192]              @ 151033344  (1536)
// M     f32  [B][192][192]         @ 151034880  (294912)
// total ~151.3 MB

// K1/K2: C[o,n] = sum_i W[o,i] * X[i,n], X fp32, out bf16.
// grid (HW/64, Cout/192, B), block 256. M-tile 192, N-tile 64, K-chunk 16.
// micro: 12 (o) x 4 (n) per thread.
__global__ __launch_bounds__(256) void conv1x1_gemm(
    const float* __restrict__ X, const float* __restrict__ Wt,
    __hip_bfloat16* __restrict__ Out, int Cout)
{
    const int b = blockIdx.z;
    const int mt = blockIdx.y;
    const int nb = blockIdx.x * 64;
    const float* Xb = X + (size_t)b * C_ * HW_;
    const float* Wb = Wt + (size_t)mt * 192 * C_;
    __hip_bfloat16* Ob = Out + ((size_t)b * Cout + (size_t)mt * 192) * HW_;

    __shared__ float Ws[16][192];
    __shared__ float Xs[16][64];

    const int t = threadIdx.x;
    const int n0 = (t & 15) * 4;
    const int og = (t >> 4) * 12;

    float acc[12][4];
#pragma unroll
    for (int i = 0; i < 12; i++)
#pragma unroll
        for (int j = 0; j < 4; j++) acc[i][j] = 0.f;

    for (int k0 = 0; k0 < C_; k0 += 16) {
#pragma unroll
        for (int j = 0; j < 12; j++) {      // stage W chunk: 16x192
            int e = t + 256 * j;
            int o = e >> 4, kk = e & 15;
            Ws[kk][o] = Wb[o * C_ + k0 + kk];
        }
#pragma unroll
        for (int j = 0; j < 4; j++) {       // stage X chunk: 16x64
            int e = t + 256 * j;
            int kk = e >> 6, n = e & 63;
            Xs[kk][n] = Xb[(size_t)(k0 + kk) * HW_ + nb + n];
        }
        __syncthreads();
#pragma unroll
        for (int kk = 0; kk < 16; kk++) {
            float4 v = *(const float4*)&Xs[kk][n0];
            float p[12];
#pragma unroll
            for (int i = 0; i < 12; i += 4) {
                float4 pw = *(const float4*)&Ws[kk][og + i];
                p[i] = pw.x; p[i + 1] = pw.y; p[i + 2] = pw.z; p[i + 3] = pw.w;
            }
#pragma unroll
            for (int i = 0; i < 12; i++) {
                acc[i][0] += p[i] * v.x; acc[i][1] += p[i] * v.y;
                acc[i][2] += p[i] * v.z; acc[i][3] += p[i] * v.w;
            }
        }
        __syncthreads();
    }
#pragma unroll
    for (int i = 0; i < 12; i++) {
        int o = og + i;
        union { ushort4 u; __hip_bfloat16 h[4]; } pk;
#pragma unroll
        for (int j = 0; j < 4; j++) pk.h[j] = __float2bfloat16(acc[i][j]);
        *(ushort4*)(Ob + (size_t)o * HW_ + nb + n0) = pk.u;
    }
}

// K3: per (b, head, 8-row tile): dwconv Q,K rows into LDS, accumulate
// G = Q K^T (raw), sum(Q^2), sum(K^2) with global atomics.
// grid (32, HEADS, B), block 256.
__global__ __launch_bounds__(256) void dw_qk_gram(
    const __hip_bfloat16* __restrict__ tmpQ,
    const __hip_bfloat16* __restrict__ tmpKV,
    const float* __restrict__ wq_dw, const float* __restrict__ wkv_dw,
    float* __restrict__ G, float* __restrict__ sq, float* __restrict__ sk)
{
    const int b = blockIdx.z, h = blockIdx.y, yt = blockIdx.x;
    const int t = threadIdx.x;
    __shared__ float Qs[CH_][257];
    __shared__ float Ks[CH_][257];
    __shared__ float wqd[CH_][9], wkd[CH_][9];
    __shared__ float sqs[CH_], sks[CH_];

    const __hip_bfloat16* Qb = tmpQ + ((size_t)b * C_ + h * CH_) * HW_;
    const __hip_bfloat16* Kb = tmpKV + ((size_t)b * 2 * C_ + h * CH_) * HW_;

    if (t < CH_ * 9) {
        wqd[t / 9][t % 9] = wq_dw[(size_t)(h * CH_) * 9 + t];
        wkd[t / 9][t % 9] = wkv_dw[(size_t)(h * CH_) * 9 + t];
    }
    if (t < CH_) { sqs[t] = 0.f; sks[t] = 0.f; }

    const int c0 = (t >> 3) * 3;   // valid for t < 64
    const int d0 = (t & 7) * 3;
    float g[3][3];
#pragma unroll
    for (int i = 0; i < 3; i++)
#pragma unroll
        for (int j = 0; j < 3; j++) g[i][j] = 0.f;

    for (int r = 0; r < 8; r++) {
        const int y = yt * 8 + r;
        __syncthreads();            // protect LDS from previous row / init
        // stage one row of Q,K via dwconv (thread = x column)
        const int x = t;
        for (int c = 0; c < CH_; c++) {
            float aq = 0.f, ak = 0.f;
            const __hip_bfloat16* qrow = Qb + (size_t)c * HW_;
            const __hip_bfloat16* krow = Kb + (size_t)c * HW_;
#pragma unroll
            for (int dy = -1; dy <= 1; dy++) {
                int yy = y + dy;
                if ((unsigned)yy >= 256u) continue;
#pragma unroll
                for (int dx = -1; dx <= 1; dx++) {
                    int xx = x + dx;
                    if ((unsigned)xx >= 256u) continue;
                    int wi = (dy + 1) * 3 + (dx + 1);
                    aq += __bfloat162float(qrow[yy * W_ + xx]) * wqd[c][wi];
                    ak += __bfloat162float(krow[yy * W_ + xx]) * wkd[c][wi];
                }
            }
            Qs[c][x] = aq; Ks[c][x] = ak;
        }
        __syncthreads();
        // norms
        if (t < 192) {
            int c = t % 24, seg = t / 24;
            float a = 0.f, bb = 0.f;
            for (int n = seg * 32; n < seg * 32 + 32; n++) {
                float q = Qs[c][n]; a += q * q;
                float k = Ks[c][n]; bb += k * k;
            }
            atomicAdd(&sqs[c], a); atomicAdd(&sks[c], bb);
        }
        // gram: 3x3 register tile, 64 threads
        if (t < 64) {
#pragma unroll 4
            for (int n = 0; n < 256; n++) {
                float qa0 = Qs[c0][n], qa1 = Qs[c0 + 1][n], qa2 = Qs[c0 + 2][n];
                float kb0 = Ks[d0][n], kb1 = Ks[d0 + 1][n], kb2 = Ks[d0 + 2][n];
                g[0][0] += qa0 * kb0; g[0][1] += qa0 * kb1; g[0][2] += qa0 * kb2;
                g[1][0] += qa1 * kb0; g[1][1] += qa1 * kb1; g[1][2] += qa1 * kb2;
                g[2][0] += qa2 * kb0; g[2][1] += qa2 * kb1; g[2][2] += qa2 * kb2;
            }
        }
    }
    if (t < 64) {
        float* Gb = G + (size_t)(b * HEADS_ + h) * CH_ * CH_;
#pragma unroll
        for (int i = 0; i < 3; i++)
#pragma unroll
            for (int j = 0; j < 3; j++)
                atomicAdd(&Gb[(c0 + i) * CH_ + d0 + j], g[i][j]);
    }
    __syncthreads();
    if (t < CH_) {
        atomicAdd(&sq[b * C_ + h * CH_ + t], sqs[t]);
        atomicAdd(&sk[b * C_ + h * CH_ + t], sks[t]);
    }
}

// K4: normalize G, softmax over d, compose M[o, h*24+d] = sum_c wproj[o,h*24+c]*attn[c][d]
// grid (HEADS, B), block 192.
__global__ __launch_bounds__(192) void softmax_proj(
    const float* __restrict__ G, const float* __restrict__ sq,
    const float* __restrict__ sk, const float* __restrict__ temperature,
    const float* __restrict__ wproj, float* __restrict__ M)
{
    const int h = blockIdx.x, b = blockIdx.y, t = threadIdx.x;
    __shared__ float attn[CH_][CH_];
    __shared__ float rk[CH_];
    const float* Gb = G + (size_t)(b * HEADS_ + h) * CH_ * CH_;
    if (t < CH_)
        rk[t] = 1.f / fmaxf(sqrtf(sk[b * C_ + h * CH_ + t]), 1e-12f);
    __syncthreads();
    if (t < CH_) {
        float rq = 1.f / fmaxf(sqrtf(sq[b * C_ + h * CH_ + t]), 1e-12f);
        float tempv = temperature[h];
        float row[CH_];
        float mx = -1e30f;
        for (int d = 0; d < CH_; d++) {
            row[d] = Gb[t * CH_ + d] * rq * rk[d] * tempv;
            mx = fmaxf(mx, row[d]);
        }
        float s = 0.f;
        for (int d = 0; d < CH_; d++) { row[d] = __expf(row[d] - mx); s += row[d]; }
        float inv = 1.f / s;
        for (int d = 0; d < CH_; d++) attn[t][d] = row[d] * inv;
    }
    __syncthreads();
    const int o = t;
    float wrow[CH_];
    for (int c = 0; c < CH_; c++) wrow[c] = wproj[o * C_ + h * CH_ + c];
    for (int d = 0; d < CH_; d++) {
        float s = 0.f;
        for (int c = 0; c < CH_; c++) s += wrow[c] * attn[c][d];
        M[((size_t)b * C_ + o) * C_ + h * CH_ + d] = s;
    }
}

// K5: out[o,n] = sum_ch M[o,ch] * V[ch,n], V = dwconv(tmpKV v-half) on the fly.
// grid (HW/64, 1, B), block 256. Same micro as K1.
__global__ __launch_bounds__(256) void attn_out_gemm(
    const __hip_bfloat16* __restrict__ tmpKV, const float* __restrict__ wkv_dw,
    const float* __restrict__ M, float* __restrict__ Out)
{
    const int b = blockIdx.z;
    const int pix0 = blockIdx.x * 64;
    const int y = pix0 >> 8;
    const int x0 = pix0 & 255;
    const __hip_bfloat16* Vb = tmpKV + ((size_t)b * 2 + 1) * (size_t)C_ * HW_;
    const float* Mb = M + (size_t)b * C_ * C_;
    float* Ob = Out + (size_t)b * C_ * HW_;

    __shared__ float Ps[16][192];
    __shared__ float Vs[16][64];
    __shared__ float wvd[C_][9];

    const int t = threadIdx.x;
    for (int e = t; e < C_ * 9; e += 256)
        wvd[e / 9][e % 9] = wkv_dw[(size_t)(C_ + e / 9) * 9 + (e % 9)];

    const int n0 = (t & 15) * 4;
    const int og = (t >> 4) * 12;
    float acc[12][4];
#pragma unroll
    for (int i = 0; i < 12; i++)
#pragma unroll
        for (int j = 0; j < 4; j++) acc[i][j] = 0.f;
    __syncthreads();

    for (int k0 = 0; k0 < C_; k0 += 16) {
#pragma unroll
        for (int j = 0; j < 12; j++) {      // stage M chunk
            int e = t + 256 * j;
            int o = e >> 4, kk = e & 15;
            Ps[kk][o] = Mb[o * C_ + k0 + kk];
        }
#pragma unroll
        for (int j = 0; j < 4; j++) {       // stage V chunk via dwconv
            int e = t + 256 * j;
            int kk = e >> 6, n = e & 63;
            int ch = k0 + kk;
            const __hip_bfloat16* base = Vb + (size_t)ch * HW_;
            float a = 0.f;
#pragma unroll
            for (int dy = -1; dy <= 1; dy++) {
                int yy = y + dy;
                if ((unsigned)yy >= 256u) continue;
#pragma unroll
                for (int dx = -1; dx <= 1; dx++) {
                    int xx = x0 + n + dx;
                    if ((unsigned)xx >= 256u) continue;
                    a += __bfloat162float(base[yy * W_ + xx]) * wvd[ch][(dy + 1) * 3 + dx + 1];
                }
            }
            Vs[kk][n] = a;
        }
        __syncthreads();
#pragma unroll
        for (int kk = 0; kk < 16; kk++) {
            float4 v = *(const float4*)&Vs[kk][n0];
            float p[12];
#pragma unroll
            for (int i = 0; i < 12; i += 4) {
                float4 pw = *(const float4*)&Ps[kk][og + i];
                p[i] = pw.x; p[i + 1] = pw.y; p[i + 2] = pw.z; p[i + 3] = pw.w;
            }
#pragma unroll
            for (int i = 0; i < 12; i++) {
                acc[i][0] += p[i] * v.x; acc[i][1] += p[i] * v.y;
                acc[i][2] += p[i] * v.z; acc[i][3] += p[i] * v.w;
            }
        }
        __syncthreads();
    }
#pragma unroll
    for (int i = 0; i < 12; i++) {
        int o = og + i;
        float4 r;
        r.x = acc[i][0]; r.y = acc[i][1]; r.z = acc[i][2]; r.w = acc[i][3];
        *(float4*)(Ob + (size_t)o * HW_ + pix0 + n0) = r;
    }
}

extern "C" void kernel_launch(void* const* d_in, const int* in_sizes, int n_in,
                              void* d_out, int out_size, void* d_ws, size_t ws_size,
                              hipStream_t stream)
{
    const float* x           = (const float*)d_in[0];
    const float* x_ref       = (const float*)d_in[1];
    const float* wq          = (const float*)d_in[2];
    const float* wq_dw       = (const float*)d_in[3];
    const float* wkv         = (const float*)d_in[4];
    const float* wkv_dw      = (const float*)d_in[5];
    const float* wproj       = (const float*)d_in[6];
    const float* temperature = (const float*)d_in[7];
    float* out = (float*)d_out;

    char* ws = (char*)d_ws;
    __hip_bfloat16* tmpQ  = (__hip_bfloat16*)(ws);
    __hip_bfloat16* tmpKV = (__hip_bfloat16*)(ws + 50331648);
    float* G  = (float*)(ws + 150994944);
    float* sq = (float*)(ws + 151031808);
    float* sk = (float*)(ws + 151033344);
    float* M  = (float*)(ws + 151034880);

    // zero the atomic accumulators (G, sq, sk are contiguous)
    hipMemsetAsync(G, 0, 36864 + 1536 + 1536, stream);

    conv1x1_gemm<<<dim3(HW_ / 64, 1, B_), 256, 0, stream>>>(x, wq, tmpQ, 192);
    conv1x1_gemm<<<dim3(HW_ / 64, 2, B_), 256, 0, stream>>>(x_ref, wkv, tmpKV, 384);
    dw_qk_gram<<<dim3(H_ / 8, HEADS_, B_), 256, 0, stream>>>(tmpQ, tmpKV, wq_dw, wkv_dw, G, sq, sk);
    softmax_proj<<<dim3(HEADS_, B_), 192, 0, stream>>>(G, sq, sk, temperature, wproj, M);
    attn_out_gemm<<<dim3(HW_ / 64, 1, B_), 256, 0, stream>>>(tmpKV, wkv_dw, M, out);
}

// Round 2
// 1331.772 us; speedup vs baseline: 1.2718x; 1.2718x over previous
//
#include <hip/hip_runtime.h>
#include <hip/hip_bf16.h>

#define B_ 2
#define C_ 192
#define HEADS_ 8
#define CH_ 24
#define H_ 256
#define W_ 256
#define HW_ 65536

// ---------------- workspace layout (bytes) ----------------
// tmpQ  bf16 [B][192][HW]          @ 0          (50331648)
// tmpKV bf16 [B][384][HW]          @ 50331648   (100663296)
// G     f32  [B][8][24][24]        @ 150994944  (36864)
// sq    f32  [B][192]              @ 151031808  (1536)
// sk    f32  [B][192]              @ 151033344  (1536)
// M     f32  [B][192][192]         @ 151034880  (294912)

__device__ __forceinline__ float b2f_us(unsigned short u) {
    return __uint_as_float(((unsigned)u) << 16);
}

// K1/K2: C[o,n] = sum_i W[o,i] * X[i,n], X fp32, out bf16.
__global__ __launch_bounds__(256) void conv1x1_gemm(
    const float* __restrict__ X, const float* __restrict__ Wt,
    __hip_bfloat16* __restrict__ Out, int Cout)
{
    const int b = blockIdx.z;
    const int mt = blockIdx.y;
    const int nb = blockIdx.x * 64;
    const float* Xb = X + (size_t)b * C_ * HW_;
    const float* Wb = Wt + (size_t)mt * 192 * C_;
    __hip_bfloat16* Ob = Out + ((size_t)b * Cout + (size_t)mt * 192) * HW_;

    __shared__ float Ws[16][192];
    __shared__ float Xs[16][64];

    const int t = threadIdx.x;
    const int n0 = (t & 15) * 4;
    const int og = (t >> 4) * 12;

    float acc[12][4];
#pragma unroll
    for (int i = 0; i < 12; i++)
#pragma unroll
        for (int j = 0; j < 4; j++) acc[i][j] = 0.f;

    for (int k0 = 0; k0 < C_; k0 += 16) {
#pragma unroll
        for (int j = 0; j < 12; j++) {
            int e = t + 256 * j;
            int o = e >> 4, kk = e & 15;
            Ws[kk][o] = Wb[o * C_ + k0 + kk];
        }
#pragma unroll
        for (int j = 0; j < 4; j++) {
            int e = t + 256 * j;
            int kk = e >> 6, n = e & 63;
            Xs[kk][n] = Xb[(size_t)(k0 + kk) * HW_ + nb + n];
        }
        __syncthreads();
#pragma unroll
        for (int kk = 0; kk < 16; kk++) {
            float4 v = *(const float4*)&Xs[kk][n0];
            float p[12];
#pragma unroll
            for (int i = 0; i < 12; i += 4) {
                float4 pw = *(const float4*)&Ws[kk][og + i];
                p[i] = pw.x; p[i + 1] = pw.y; p[i + 2] = pw.z; p[i + 3] = pw.w;
            }
#pragma unroll
            for (int i = 0; i < 12; i++) {
                acc[i][0] += p[i] * v.x; acc[i][1] += p[i] * v.y;
                acc[i][2] += p[i] * v.z; acc[i][3] += p[i] * v.w;
            }
        }
        __syncthreads();
    }
#pragma unroll
    for (int i = 0; i < 12; i++) {
        int o = og + i;
        union { ushort4 u; __hip_bfloat16 h[4]; } pk;
#pragma unroll
        for (int j = 0; j < 4; j++) pk.h[j] = __float2bfloat16(acc[i][j]);
        *(ushort4*)(Ob + (size_t)o * HW_ + nb + n0) = pk.u;
    }
}

// K3 (rewritten): one block = (b, h, row y). 192 threads compute dwconv of Q,K
// for (channel c = t>>3, 32-px segment s8 = t&7) with uint4 bf16x8 loads.
// Conv rows land in LDS f32 [24][260]; Gram runs on all 256 threads as
// 16 tiles (6x6) x 16 pixel-segments with float4 LDS reads, shfl-reduced.
#define PADW 260
__global__ __launch_bounds__(256) void dw_qk_gram(
    const __hip_bfloat16* __restrict__ tmpQ,
    const __hip_bfloat16* __restrict__ tmpKV,
    const float* __restrict__ wq_dw, const float* __restrict__ wkv_dw,
    float* __restrict__ G, float* __restrict__ sq, float* __restrict__ sk)
{
    const int y = blockIdx.x, h = blockIdx.y, b = blockIdx.z;
    const int t = threadIdx.x;

    __shared__ char smem[2 * CH_ * PADW * 4];       // Qs | Ks ; aliased by Gp later
    __shared__ float sqs[CH_], sks[CH_];
    float* Qs = (float*)smem;
    float* Ks = Qs + CH_ * PADW;
    float* Gp = (float*)smem;                        // [4][576] alias (after sync)

    if (t < CH_) { sqs[t] = 0.f; sks[t] = 0.f; }
    __syncthreads();

    // ---- conv phase: 192 threads ----
    if (t < 192) {
        const int c = t >> 3;
        const int x0 = (t & 7) * 32;
        const unsigned short* Qb = (const unsigned short*)(tmpQ + ((size_t)b * C_ + h * CH_ + c) * HW_);
        const unsigned short* Kb = (const unsigned short*)(tmpKV + ((size_t)b * 2 * C_ + h * CH_ + c) * HW_);
        const float* wqw = wq_dw + (size_t)(h * CH_ + c) * 9;
        const float* wkw = wkv_dw + (size_t)(h * CH_ + c) * 9;

#pragma unroll
        for (int tens = 0; tens < 2; tens++) {
            const unsigned short* base = tens ? Kb : Qb;
            const float* wp = tens ? wkw : wqw;
            float o[32];
#pragma unroll
            for (int i = 0; i < 32; i++) o[i] = 0.f;
#pragma unroll
            for (int dy = -1; dy <= 1; dy++) {
                int yy = y + dy;
                if ((unsigned)yy >= 256u) continue;
                const unsigned short* r = base + yy * W_;
                float v[34];
                v[0]  = (x0 > 0) ? b2f_us(r[x0 - 1]) : 0.f;
                v[33] = (x0 + 32 < 256) ? b2f_us(r[x0 + 32]) : 0.f;
                const uint4* r4 = (const uint4*)(r + x0);
#pragma unroll
                for (int m = 0; m < 4; m++) {
                    uint4 raw = r4[m];
                    unsigned u;
                    u = raw.x; v[1 + 8*m + 0] = __uint_as_float(u << 16); v[1 + 8*m + 1] = __uint_as_float(u & 0xffff0000u);
                    u = raw.y; v[1 + 8*m + 2] = __uint_as_float(u << 16); v[1 + 8*m + 3] = __uint_as_float(u & 0xffff0000u);
                    u = raw.z; v[1 + 8*m + 4] = __uint_as_float(u << 16); v[1 + 8*m + 5] = __uint_as_float(u & 0xffff0000u);
                    u = raw.w; v[1 + 8*m + 6] = __uint_as_float(u << 16); v[1 + 8*m + 7] = __uint_as_float(u & 0xffff0000u);
                }
                float w0 = wp[3 * (dy + 1) + 0];
                float w1 = wp[3 * (dy + 1) + 1];
                float w2 = wp[3 * (dy + 1) + 2];
#pragma unroll
                for (int i = 0; i < 32; i++)
                    o[i] += v[i] * w0 + v[i + 1] * w1 + v[i + 2] * w2;
            }
            float s = 0.f;
#pragma unroll
            for (int i = 0; i < 32; i++) s += o[i] * o[i];
            float* dst = (tens ? Ks : Qs) + c * PADW + x0;
#pragma unroll
            for (int m = 0; m < 8; m++) {
                float4 w4; w4.x = o[4*m]; w4.y = o[4*m+1]; w4.z = o[4*m+2]; w4.w = o[4*m+3];
                *(float4*)(dst + 4 * m) = w4;
            }
            atomicAdd(tens ? &sks[c] : &sqs[c], s);
        }
    }
    __syncthreads();

    // ---- gram phase: all 256 threads. tile = 6x6 of G, 16-px segment ----
    const int tile = t & 15, seg = t >> 4;
    const int c0 = (tile >> 2) * 6, d0 = (tile & 3) * 6;
    float g[6][6];
#pragma unroll
    for (int i = 0; i < 6; i++)
#pragma unroll
        for (int j = 0; j < 6; j++) g[i][j] = 0.f;

    for (int n = seg * 16; n < seg * 16 + 16; n += 4) {
        float4 qv[6], kv[6];
#pragma unroll
        for (int i = 0; i < 6; i++) qv[i] = *(const float4*)(Qs + (c0 + i) * PADW + n);
#pragma unroll
        for (int j = 0; j < 6; j++) kv[j] = *(const float4*)(Ks + (d0 + j) * PADW + n);
#pragma unroll
        for (int i = 0; i < 6; i++)
#pragma unroll
            for (int j = 0; j < 6; j++)
                g[i][j] += qv[i].x * kv[j].x + qv[i].y * kv[j].y +
                           qv[i].z * kv[j].z + qv[i].w * kv[j].w;
    }
    __syncthreads();   // Qs/Ks reads done; smem may be reused as Gp

    // reduce 4 segments within each wave (lanes l, l+16, l+32, l+48 share tile)
    const int w = t >> 6, lane = t & 63;
#pragma unroll
    for (int i = 0; i < 6; i++)
#pragma unroll
        for (int j = 0; j < 6; j++) {
            float v = g[i][j];
            v += __shfl_down(v, 32);
            v += __shfl_down(v, 16);
            g[i][j] = v;
        }
    if (lane < 16) {
        float* dst = Gp + (w * 16 + lane) * 36;
#pragma unroll
        for (int i = 0; i < 6; i++)
#pragma unroll
            for (int j = 0; j < 6; j++) dst[i * 6 + j] = g[i][j];
    }
    __syncthreads();

    float* Gb = G + (size_t)(b * HEADS_ + h) * CH_ * CH_;
    for (int e = t; e < 576; e += 256) {
        int tl = e / 36, k = e % 36;
        float v = Gp[e] + Gp[576 + e] + Gp[1152 + e] + Gp[1728 + e];
        int cc = (tl >> 2) * 6 + k / 6;
        int dd = (tl & 3) * 6 + k % 6;
        atomicAdd(&Gb[cc * CH_ + dd], v);
    }
    if (t < CH_) {
        atomicAdd(&sq[b * C_ + h * CH_ + t], sqs[t]);
        atomicAdd(&sk[b * C_ + h * CH_ + t], sks[t]);
    }
}

// K4: normalize G, softmax, compose M
__global__ __launch_bounds__(192) void softmax_proj(
    const float* __restrict__ G, const float* __restrict__ sq,
    const float* __restrict__ sk, const float* __restrict__ temperature,
    const float* __restrict__ wproj, float* __restrict__ M)
{
    const int h = blockIdx.x, b = blockIdx.y, t = threadIdx.x;
    __shared__ float attn[CH_][CH_];
    __shared__ float rk[CH_];
    const float* Gb = G + (size_t)(b * HEADS_ + h) * CH_ * CH_;
    if (t < CH_)
        rk[t] = 1.f / fmaxf(sqrtf(sk[b * C_ + h * CH_ + t]), 1e-12f);
    __syncthreads();
    if (t < CH_) {
        float rq = 1.f / fmaxf(sqrtf(sq[b * C_ + h * CH_ + t]), 1e-12f);
        float tempv = temperature[h];
        float row[CH_];
        float mx = -1e30f;
        for (int d = 0; d < CH_; d++) {
            row[d] = Gb[t * CH_ + d] * rq * rk[d] * tempv;
            mx = fmaxf(mx, row[d]);
        }
        float s = 0.f;
        for (int d = 0; d < CH_; d++) { row[d] = __expf(row[d] - mx); s += row[d]; }
        float inv = 1.f / s;
        for (int d = 0; d < CH_; d++) attn[t][d] = row[d] * inv;
    }
    __syncthreads();
    const int o = t;
    float wrow[CH_];
    for (int c = 0; c < CH_; c++) wrow[c] = wproj[o * C_ + h * CH_ + c];
    for (int d = 0; d < CH_; d++) {
        float s = 0.f;
        for (int c = 0; c < CH_; c++) s += wrow[c] * attn[c][d];
        M[((size_t)b * C_ + o) * C_ + h * CH_ + d] = s;
    }
}

// K5: out[o,n] = sum_ch M[o,ch] * V[ch,n], V = dwconv(tmpKV v-half) on the fly.
__global__ __launch_bounds__(256) void attn_out_gemm(
    const __hip_bfloat16* __restrict__ tmpKV, const float* __restrict__ wkv_dw,
    const float* __restrict__ M, float* __restrict__ Out)
{
    const int b = blockIdx.z;
    const int pix0 = blockIdx.x * 64;
    const int y = pix0 >> 8;
    const int x0 = pix0 & 255;
    const __hip_bfloat16* Vb = tmpKV + ((size_t)b * 2 + 1) * (size_t)C_ * HW_;
    const float* Mb = M + (size_t)b * C_ * C_;
    float* Ob = Out + (size_t)b * C_ * HW_;

    __shared__ float Ps[16][192];
    __shared__ float Vs[16][64];
    __shared__ float wvd[C_][9];

    const int t = threadIdx.x;
    for (int e = t; e < C_ * 9; e += 256)
        wvd[e / 9][e % 9] = wkv_dw[(size_t)(C_ + e / 9) * 9 + (e % 9)];

    const int n0 = (t & 15) * 4;
    const int og = (t >> 4) * 12;
    float acc[12][4];
#pragma unroll
    for (int i = 0; i < 12; i++)
#pragma unroll
        for (int j = 0; j < 4; j++) acc[i][j] = 0.f;
    __syncthreads();

    for (int k0 = 0; k0 < C_; k0 += 16) {
#pragma unroll
        for (int j = 0; j < 12; j++) {
            int e = t + 256 * j;
            int o = e >> 4, kk = e & 15;
            Ps[kk][o] = Mb[o * C_ + k0 + kk];
        }
#pragma unroll
        for (int j = 0; j < 4; j++) {
            int e = t + 256 * j;
            int kk = e >> 6, n = e & 63;
            int ch = k0 + kk;
            const __hip_bfloat16* base = Vb + (size_t)ch * HW_;
            float a = 0.f;
#pragma unroll
            for (int dy = -1; dy <= 1; dy++) {
                int yy = y + dy;
                if ((unsigned)yy >= 256u) continue;
#pragma unroll
                for (int dx = -1; dx <= 1; dx++) {
                    int xx = x0 + n + dx;
                    if ((unsigned)xx >= 256u) continue;
                    a += __bfloat162float(base[yy * W_ + xx]) * wvd[ch][(dy + 1) * 3 + dx + 1];
                }
            }
            Vs[kk][n] = a;
        }
        __syncthreads();
#pragma unroll
        for (int kk = 0; kk < 16; kk++) {
            float4 v = *(const float4*)&Vs[kk][n0];
            float p[12];
#pragma unroll
            for (int i = 0; i < 12; i += 4) {
                float4 pw = *(const float4*)&Ps[kk][og + i];
                p[i] = pw.x; p[i + 1] = pw.y; p[i + 2] = pw.z; p[i + 3] = pw.w;
            }
#pragma unroll
            for (int i = 0; i < 12; i++) {
                acc[i][0] += p[i] * v.x; acc[i][1] += p[i] * v.y;
                acc[i][2] += p[i] * v.z; acc[i][3] += p[i] * v.w;
            }
        }
        __syncthreads();
    }
#pragma unroll
    for (int i = 0; i < 12; i++) {
        int o = og + i;
        float4 r;
        r.x = acc[i][0]; r.y = acc[i][1]; r.z = acc[i][2]; r.w = acc[i][3];
        *(float4*)(Ob + (size_t)o * HW_ + pix0 + n0) = r;
    }
}

extern "C" void kernel_launch(void* const* d_in, const int* in_sizes, int n_in,
                              void* d_out, int out_size, void* d_ws, size_t ws_size,
                              hipStream_t stream)
{
    const float* x           = (const float*)d_in[0];
    const float* x_ref       = (const float*)d_in[1];
    const float* wq          = (const float*)d_in[2];
    const float* wq_dw       = (const float*)d_in[3];
    const float* wkv         = (const float*)d_in[4];
    const float* wkv_dw      = (const float*)d_in[5];
    const float* wproj       = (const float*)d_in[6];
    const float* temperature = (const float*)d_in[7];
    float* out = (float*)d_out;

    char* ws = (char*)d_ws;
    __hip_bfloat16* tmpQ  = (__hip_bfloat16*)(ws);
    __hip_bfloat16* tmpKV = (__hip_bfloat16*)(ws + 50331648);
    float* G  = (float*)(ws + 150994944);
    float* sq = (float*)(ws + 151031808);
    float* sk = (float*)(ws + 151033344);
    float* M  = (float*)(ws + 151034880);

    hipMemsetAsync(G, 0, 36864 + 1536 + 1536, stream);

    conv1x1_gemm<<<dim3(HW_ / 64, 1, B_), 256, 0, stream>>>(x, wq, tmpQ, 192);
    conv1x1_gemm<<<dim3(HW_ / 64, 2, B_), 256, 0, stream>>>(x_ref, wkv, tmpKV, 384);
    dw_qk_gram<<<dim3(H_, HEADS_, B_), 256, 0, stream>>>(tmpQ, tmpKV, wq_dw, wkv_dw, G, sq, sk);
    softmax_proj<<<dim3(HEADS_, B_), 192, 0, stream>>>(G, sq, sk, temperature, wproj, M);
    attn_out_gemm<<<dim3(HW_ / 64, 1, B_), 256, 0, stream>>>(tmpKV, wkv_dw, M, out);
}

// Round 3
// 563.214 us; speedup vs baseline: 3.0074x; 2.3646x over previous
//
#include <hip/hip_runtime.h>
#include <hip/hip_bf16.h>

#define B_ 2
#define C_ 192
#define HEADS_ 8
#define CH_ 24
#define H_ 256
#define W_ 256
#define HW_ 65536

// ---------------- workspace layout (bytes) ----------------
// tmpQ  bf16 [B][192][HW]   @ 0           (50331648)   } tmpV aliases tmpQ
// tmpKV bf16 [B][384][HW]   @ 50331648    (100663296)  } (K3 consumes tmpQ first)
// G     f32  [B][8][24][24] @ 150994944   (36864)
// sq    f32  [B][192]       @ 151031808   (1536)
// sk    f32  [B][192]       @ 151033344   (1536)
// M     f32  [B][192][192]  @ 151034880   (294912)

using bf16x8 = __attribute__((ext_vector_type(8))) __bf16;
using f32x4  = __attribute__((ext_vector_type(4))) float;

__device__ __forceinline__ float b2f_us(unsigned short u) {
    return __uint_as_float(((unsigned)u) << 16);
}
__device__ __forceinline__ unsigned short f2bf(float f) {
    union { __hip_bfloat16 b; unsigned short u; } cv;
    cv.b = __float2bfloat16(f);
    return cv.u;
}

// ---------------------------------------------------------------------------
// MFMA GEMM: Out[o, n] = sum_k A[o, k] * B[k, n];  K = 192, N-tile = 64,
// M-tile = 192 (4 waves x 48 rows). A fp32 (-> bf16 in staging). B either
// fp32 (x / x_ref) or bf16 (tmpV). Out either bf16 (tmpQ/tmpKV) or f32 (out).
// LDS: Al[o][k] pitch 40 bf16; Bl[rB][k] pitch 40, rB = ((p&3)<<4)|(p>>2)
// so lane li's 4 n-frags are pixels 4*li .. 4*li+3 (contiguous epilogue).
// ---------------------------------------------------------------------------
template<bool B_F32, bool OUT_F32>
__global__ __launch_bounds__(256) void gemm_mfma(
    const float* __restrict__ A, long a_bstride,
    const void* __restrict__ Bv, void* __restrict__ Outv, int outC)
{
    const int nb = blockIdx.x * 64;
    const int mt = blockIdx.y;
    const int b  = blockIdx.z;
    const int t  = threadIdx.x;

    __shared__ unsigned short Al[192 * 40];
    __shared__ unsigned short Bl[64 * 40];

    const float* Ab = A + (size_t)b * a_bstride + (size_t)mt * 192 * 192;

    const int w = t >> 6, l = t & 63, li = l & 15, q = l >> 4;

    f32x4 acc[3][4];
#pragma unroll
    for (int mi = 0; mi < 3; mi++)
#pragma unroll
        for (int ni = 0; ni < 4; ni++)
            acc[mi][ni] = (f32x4){0.f, 0.f, 0.f, 0.f};

    const int p0 = (t & 15) * 4;   // B staging: pixel group
    const int kp = t >> 4;         // B staging: k-pair index (0..15)

    for (int kc = 0; kc < 6; kc++) {
        const int k0 = kc * 32;

        // ---- stage A chunk: 192 x 32 fp32 -> bf16 ----
#pragma unroll
        for (int j = 0; j < 6; j++) {
            int e = t + 256 * j;
            int o = e >> 3, kq = e & 7;
            float4 va = *(const float4*)(Ab + (size_t)o * 192 + k0 + kq * 4);
            ushort4 u;
            u.x = f2bf(va.x); u.y = f2bf(va.y); u.z = f2bf(va.z); u.w = f2bf(va.w);
            *(ushort4*)&Al[o * 40 + kq * 4] = u;
        }

        // ---- stage B chunk: 32 x 64, transposed into Bl[rB][k] ----
        {
            const int k = k0 + kp * 2;
            unsigned int packed[4];
            if (B_F32) {
                const float* Bb = (const float*)Bv + (size_t)b * 192 * HW_;
                float4 r0 = *(const float4*)(Bb + (size_t)k * HW_ + nb + p0);
                float4 r1 = *(const float4*)(Bb + (size_t)(k + 1) * HW_ + nb + p0);
                packed[0] = (unsigned)f2bf(r0.x) | ((unsigned)f2bf(r1.x) << 16);
                packed[1] = (unsigned)f2bf(r0.y) | ((unsigned)f2bf(r1.y) << 16);
                packed[2] = (unsigned)f2bf(r0.z) | ((unsigned)f2bf(r1.z) << 16);
                packed[3] = (unsigned)f2bf(r0.w) | ((unsigned)f2bf(r1.w) << 16);
            } else {
                const unsigned short* Bb = (const unsigned short*)Bv + (size_t)b * 192 * HW_;
                ushort4 r0 = *(const ushort4*)(Bb + (size_t)k * HW_ + nb + p0);
                ushort4 r1 = *(const ushort4*)(Bb + (size_t)(k + 1) * HW_ + nb + p0);
                packed[0] = (unsigned)r0.x | ((unsigned)r1.x << 16);
                packed[1] = (unsigned)r0.y | ((unsigned)r1.y << 16);
                packed[2] = (unsigned)r0.z | ((unsigned)r1.z << 16);
                packed[3] = (unsigned)r0.w | ((unsigned)r1.w << 16);
            }
#pragma unroll
            for (int c = 0; c < 4; c++) {
                int p = p0 + c;
                int rB = ((p & 3) << 4) | (p >> 2);
                *(unsigned int*)&Bl[rB * 40 + kp * 2] = packed[c];
            }
        }
        __syncthreads();

        // ---- fragments + MFMA ----
        bf16x8 af[3], bfr[4];
#pragma unroll
        for (int mi = 0; mi < 3; mi++)
            af[mi] = *(const bf16x8*)&Al[(w * 48 + mi * 16 + li) * 40 + q * 8];
#pragma unroll
        for (int ni = 0; ni < 4; ni++)
            bfr[ni] = *(const bf16x8*)&Bl[(ni * 16 + li) * 40 + q * 8];
#pragma unroll
        for (int mi = 0; mi < 3; mi++)
#pragma unroll
            for (int ni = 0; ni < 4; ni++)
                acc[mi][ni] = __builtin_amdgcn_mfma_f32_16x16x32_bf16(
                    af[mi], bfr[ni], acc[mi][ni], 0, 0, 0);
        __syncthreads();
    }

    // ---- epilogue: lane li holds pixels nb+4*li .. +3 (regs ni), rows q*4+r ----
    if (OUT_F32) {
        float* Ob = (float*)Outv + ((size_t)b * outC + (size_t)mt * 192) * HW_;
#pragma unroll
        for (int mi = 0; mi < 3; mi++)
#pragma unroll
            for (int r = 0; r < 4; r++) {
                int o = w * 48 + mi * 16 + q * 4 + r;
                float4 vv;
                vv.x = acc[mi][0][r]; vv.y = acc[mi][1][r];
                vv.z = acc[mi][2][r]; vv.w = acc[mi][3][r];
                *(float4*)(Ob + (size_t)o * HW_ + nb + 4 * li) = vv;
            }
    } else {
        unsigned short* Ob = (unsigned short*)Outv + ((size_t)b * outC + (size_t)mt * 192) * HW_;
#pragma unroll
        for (int mi = 0; mi < 3; mi++)
#pragma unroll
            for (int r = 0; r < 4; r++) {
                int o = w * 48 + mi * 16 + q * 4 + r;
                ushort4 u;
                u.x = f2bf(acc[mi][0][r]); u.y = f2bf(acc[mi][1][r]);
                u.z = f2bf(acc[mi][2][r]); u.w = f2bf(acc[mi][3][r]);
                *(ushort4*)(Ob + (size_t)o * HW_ + nb + 4 * li) = u;
            }
    }
}

// ---------------------------------------------------------------------------
// dwconv_v: V = dwconv3x3(tmpKV v-half), bf16 out. grid (H, 6, B);
// thread = (channel c = cg*32 + t>>3, 32-px segment).
// ---------------------------------------------------------------------------
__global__ __launch_bounds__(256) void dwconv_v(
    const __hip_bfloat16* __restrict__ tmpKV, const float* __restrict__ wkv_dw,
    __hip_bfloat16* __restrict__ V)
{
    const int y = blockIdx.x, cg = blockIdx.y, b = blockIdx.z;
    const int t = threadIdx.x;
    const int c = cg * 32 + (t >> 3);
    const int x0 = (t & 7) * 32;
    const unsigned short* base =
        (const unsigned short*)(tmpKV + ((size_t)b * 2 * C_ + C_ + c) * HW_);
    const float* wp = wkv_dw + (size_t)(C_ + c) * 9;
    float wgt[9];
#pragma unroll
    for (int i = 0; i < 9; i++) wgt[i] = wp[i];

    float o[32];
#pragma unroll
    for (int i = 0; i < 32; i++) o[i] = 0.f;

#pragma unroll
    for (int dy = -1; dy <= 1; dy++) {
        int yy = y + dy;
        if ((unsigned)yy >= 256u) continue;
        const unsigned short* r = base + yy * W_;
        float v[34];
        v[0]  = (x0 > 0) ? b2f_us(r[x0 - 1]) : 0.f;
        v[33] = (x0 + 32 < 256) ? b2f_us(r[x0 + 32]) : 0.f;
        const uint4* r4 = (const uint4*)(r + x0);
#pragma unroll
        for (int m = 0; m < 4; m++) {
            uint4 raw = r4[m];
            unsigned u;
            u = raw.x; v[1 + 8*m + 0] = __uint_as_float(u << 16); v[1 + 8*m + 1] = __uint_as_float(u & 0xffff0000u);
            u = raw.y; v[1 + 8*m + 2] = __uint_as_float(u << 16); v[1 + 8*m + 3] = __uint_as_float(u & 0xffff0000u);
            u = raw.z; v[1 + 8*m + 4] = __uint_as_float(u << 16); v[1 + 8*m + 5] = __uint_as_float(u & 0xffff0000u);
            u = raw.w; v[1 + 8*m + 6] = __uint_as_float(u << 16); v[1 + 8*m + 7] = __uint_as_float(u & 0xffff0000u);
        }
        float w0 = wgt[3 * (dy + 1) + 0];
        float w1 = wgt[3 * (dy + 1) + 1];
        float w2 = wgt[3 * (dy + 1) + 2];
#pragma unroll
        for (int i = 0; i < 32; i++)
            o[i] += v[i] * w0 + v[i + 1] * w1 + v[i + 2] * w2;
    }
    unsigned short* dst = (unsigned short*)V + ((size_t)b * C_ + c) * HW_ + y * W_ + x0;
#pragma unroll
    for (int m = 0; m < 4; m++) {
        uint4 pk;
        pk.x = (unsigned)f2bf(o[8*m + 0]) | ((unsigned)f2bf(o[8*m + 1]) << 16);
        pk.y = (unsigned)f2bf(o[8*m + 2]) | ((unsigned)f2bf(o[8*m + 3]) << 16);
        pk.z = (unsigned)f2bf(o[8*m + 4]) | ((unsigned)f2bf(o[8*m + 5]) << 16);
        pk.w = (unsigned)f2bf(o[8*m + 6]) | ((unsigned)f2bf(o[8*m + 7]) << 16);
        *(uint4*)(dst + 8 * m) = pk;
    }
}

// ---------------------------------------------------------------------------
// K3: per (b, h, row y): dwconv Q,K -> LDS, Gram + norms.
// ---------------------------------------------------------------------------
#define PADW 260
__global__ __launch_bounds__(256) void dw_qk_gram(
    const __hip_bfloat16* __restrict__ tmpQ,
    const __hip_bfloat16* __restrict__ tmpKV,
    const float* __restrict__ wq_dw, const float* __restrict__ wkv_dw,
    float* __restrict__ G, float* __restrict__ sq, float* __restrict__ sk)
{
    const int y = blockIdx.x, h = blockIdx.y, b = blockIdx.z;
    const int t = threadIdx.x;

    __shared__ char smem[2 * CH_ * PADW * 4];
    __shared__ float sqs[CH_], sks[CH_];
    float* Qs = (float*)smem;
    float* Ks = Qs + CH_ * PADW;
    float* Gp = (float*)smem;

    if (t < CH_) { sqs[t] = 0.f; sks[t] = 0.f; }
    __syncthreads();

    if (t < 192) {
        const int c = t >> 3;
        const int x0 = (t & 7) * 32;
        const unsigned short* Qb = (const unsigned short*)(tmpQ + ((size_t)b * C_ + h * CH_ + c) * HW_);
        const unsigned short* Kb = (const unsigned short*)(tmpKV + ((size_t)b * 2 * C_ + h * CH_ + c) * HW_);
        const float* wqw = wq_dw + (size_t)(h * CH_ + c) * 9;
        const float* wkw = wkv_dw + (size_t)(h * CH_ + c) * 9;

#pragma unroll
        for (int tens = 0; tens < 2; tens++) {
            const unsigned short* base = tens ? Kb : Qb;
            const float* wp = tens ? wkw : wqw;
            float o[32];
#pragma unroll
            for (int i = 0; i < 32; i++) o[i] = 0.f;
#pragma unroll
            for (int dy = -1; dy <= 1; dy++) {
                int yy = y + dy;
                if ((unsigned)yy >= 256u) continue;
                const unsigned short* r = base + yy * W_;
                float v[34];
                v[0]  = (x0 > 0) ? b2f_us(r[x0 - 1]) : 0.f;
                v[33] = (x0 + 32 < 256) ? b2f_us(r[x0 + 32]) : 0.f;
                const uint4* r4 = (const uint4*)(r + x0);
#pragma unroll
                for (int m = 0; m < 4; m++) {
                    uint4 raw = r4[m];
                    unsigned u;
                    u = raw.x; v[1 + 8*m + 0] = __uint_as_float(u << 16); v[1 + 8*m + 1] = __uint_as_float(u & 0xffff0000u);
                    u = raw.y; v[1 + 8*m + 2] = __uint_as_float(u << 16); v[1 + 8*m + 3] = __uint_as_float(u & 0xffff0000u);
                    u = raw.z; v[1 + 8*m + 4] = __uint_as_float(u << 16); v[1 + 8*m + 5] = __uint_as_float(u & 0xffff0000u);
                    u = raw.w; v[1 + 8*m + 6] = __uint_as_float(u << 16); v[1 + 8*m + 7] = __uint_as_float(u & 0xffff0000u);
                }
                float w0 = wp[3 * (dy + 1) + 0];
                float w1 = wp[3 * (dy + 1) + 1];
                float w2 = wp[3 * (dy + 1) + 2];
#pragma unroll
                for (int i = 0; i < 32; i++)
                    o[i] += v[i] * w0 + v[i + 1] * w1 + v[i + 2] * w2;
            }
            float s = 0.f;
#pragma unroll
            for (int i = 0; i < 32; i++) s += o[i] * o[i];
            float* dst = (tens ? Ks : Qs) + c * PADW + x0;
#pragma unroll
            for (int m = 0; m < 8; m++) {
                float4 w4; w4.x = o[4*m]; w4.y = o[4*m+1]; w4.z = o[4*m+2]; w4.w = o[4*m+3];
                *(float4*)(dst + 4 * m) = w4;
            }
            atomicAdd(tens ? &sks[c] : &sqs[c], s);
        }
    }
    __syncthreads();

    const int tile = t & 15, seg = t >> 4;
    const int c0 = (tile >> 2) * 6, d0 = (tile & 3) * 6;
    float g[6][6];
#pragma unroll
    for (int i = 0; i < 6; i++)
#pragma unroll
        for (int j = 0; j < 6; j++) g[i][j] = 0.f;

    for (int n = seg * 16; n < seg * 16 + 16; n += 4) {
        float4 qv[6], kv[6];
#pragma unroll
        for (int i = 0; i < 6; i++) qv[i] = *(const float4*)(Qs + (c0 + i) * PADW + n);
#pragma unroll
        for (int j = 0; j < 6; j++) kv[j] = *(const float4*)(Ks + (d0 + j) * PADW + n);
#pragma unroll
        for (int i = 0; i < 6; i++)
#pragma unroll
            for (int j = 0; j < 6; j++)
                g[i][j] += qv[i].x * kv[j].x + qv[i].y * kv[j].y +
                           qv[i].z * kv[j].z + qv[i].w * kv[j].w;
    }
    __syncthreads();

    const int w = t >> 6, lane = t & 63;
#pragma unroll
    for (int i = 0; i < 6; i++)
#pragma unroll
        for (int j = 0; j < 6; j++) {
            float v = g[i][j];
            v += __shfl_down(v, 32);
            v += __shfl_down(v, 16);
            g[i][j] = v;
        }
    if (lane < 16) {
        float* dst = Gp + (w * 16 + lane) * 36;
#pragma unroll
        for (int i = 0; i < 6; i++)
#pragma unroll
            for (int j = 0; j < 6; j++) dst[i * 6 + j] = g[i][j];
    }
    __syncthreads();

    float* Gb = G + (size_t)(b * HEADS_ + h) * CH_ * CH_;
    for (int e = t; e < 576; e += 256) {
        int tl = e / 36, k = e % 36;
        float v = Gp[e] + Gp[576 + e] + Gp[1152 + e] + Gp[1728 + e];
        int cc = (tl >> 2) * 6 + k / 6;
        int dd = (tl & 3) * 6 + k % 6;
        atomicAdd(&Gb[cc * CH_ + dd], v);
    }
    if (t < CH_) {
        atomicAdd(&sq[b * C_ + h * CH_ + t], sqs[t]);
        atomicAdd(&sk[b * C_ + h * CH_ + t], sks[t]);
    }
}

// K4: normalize G, softmax, compose M
__global__ __launch_bounds__(192) void softmax_proj(
    const float* __restrict__ G, const float* __restrict__ sq,
    const float* __restrict__ sk, const float* __restrict__ temperature,
    const float* __restrict__ wproj, float* __restrict__ M)
{
    const int h = blockIdx.x, b = blockIdx.y, t = threadIdx.x;
    __shared__ float attn[CH_][CH_];
    __shared__ float rk[CH_];
    const float* Gb = G + (size_t)(b * HEADS_ + h) * CH_ * CH_;
    if (t < CH_)
        rk[t] = 1.f / fmaxf(sqrtf(sk[b * C_ + h * CH_ + t]), 1e-12f);
    __syncthreads();
    if (t < CH_) {
        float rq = 1.f / fmaxf(sqrtf(sq[b * C_ + h * CH_ + t]), 1e-12f);
        float tempv = temperature[h];
        float row[CH_];
        float mx = -1e30f;
        for (int d = 0; d < CH_; d++) {
            row[d] = Gb[t * CH_ + d] * rq * rk[d] * tempv;
            mx = fmaxf(mx, row[d]);
        }
        float s = 0.f;
        for (int d = 0; d < CH_; d++) { row[d] = __expf(row[d] - mx); s += row[d]; }
        float inv = 1.f / s;
        for (int d = 0; d < CH_; d++) attn[t][d] = row[d] * inv;
    }
    __syncthreads();
    const int o = t;
    float wrow[CH_];
    for (int c = 0; c < CH_; c++) wrow[c] = wproj[o * C_ + h * CH_ + c];
    for (int d = 0; d < CH_; d++) {
        float s = 0.f;
        for (int c = 0; c < CH_; c++) s += wrow[c] * attn[c][d];
        M[((size_t)b * C_ + o) * C_ + h * CH_ + d] = s;
    }
}

extern "C" void kernel_launch(void* const* d_in, const int* in_sizes, int n_in,
                              void* d_out, int out_size, void* d_ws, size_t ws_size,
                              hipStream_t stream)
{
    const float* x           = (const float*)d_in[0];
    const float* x_ref       = (const float*)d_in[1];
    const float* wq          = (const float*)d_in[2];
    const float* wq_dw       = (const float*)d_in[3];
    const float* wkv         = (const float*)d_in[4];
    const float* wkv_dw      = (const float*)d_in[5];
    const float* wproj       = (const float*)d_in[6];
    const float* temperature = (const float*)d_in[7];
    float* out = (float*)d_out;

    char* ws = (char*)d_ws;
    __hip_bfloat16* tmpQ  = (__hip_bfloat16*)(ws);
    __hip_bfloat16* tmpKV = (__hip_bfloat16*)(ws + 50331648);
    __hip_bfloat16* tmpV  = (__hip_bfloat16*)(ws);          // aliases tmpQ (safe: K3 before dwconv_v)
    float* G  = (float*)(ws + 150994944);
    float* sq = (float*)(ws + 151031808);
    float* sk = (float*)(ws + 151033344);
    float* M  = (float*)(ws + 151034880);

    hipMemsetAsync(G, 0, 36864 + 1536 + 1536, stream);

    // K1: q1x1 = wq @ x          -> tmpQ (bf16)
    gemm_mfma<true, false><<<dim3(HW_ / 64, 1, B_), 256, 0, stream>>>(
        wq, 0, x, tmpQ, 192);
    // K2: kv1x1 = wkv @ x_ref    -> tmpKV (bf16)
    gemm_mfma<true, false><<<dim3(HW_ / 64, 2, B_), 256, 0, stream>>>(
        wkv, 0, x_ref, tmpKV, 384);
    // K3: dwconv q,k + gram + norms
    dw_qk_gram<<<dim3(H_, HEADS_, B_), 256, 0, stream>>>(
        tmpQ, tmpKV, wq_dw, wkv_dw, G, sq, sk);
    // K4: softmax + compose M
    softmax_proj<<<dim3(HEADS_, B_), 192, 0, stream>>>(
        G, sq, sk, temperature, wproj, M);
    // dwconv of V (overwrites tmpQ region)
    dwconv_v<<<dim3(H_, 6, B_), 256, 0, stream>>>(tmpKV, wkv_dw, tmpV);
    // K5: out = M @ V            -> out (f32)
    gemm_mfma<false, true><<<dim3(HW_ / 64, 1, B_), 256, 0, stream>>>(
        M, 192 * 192, tmpV, out, 192);
}